// Round 3
// baseline (5224.204 us; speedup 1.0000x reference)
//
#include <hip/hip_runtime.h>
#include <hip/hip_cooperative_groups.h>
#include <stdint.h>
#include <stddef.h>

namespace cg = cooperative_groups;

#define B_ 64
#define L_ 200
#define F_ 512
#define H_ 512
#define A_ 512
#define E_ 512
#define V_ 50257
#define T_ 21
#define D_ 1024
#define NBLK_LOG 786   /* ceil(V/64) */
#define NPART 3144     /* NBLK_LOG*4 waves */
#define NB_COOP 512
#define NG_COOP 448    /* gemm blocks; last 64 are attention blocks */

typedef __attribute__((ext_vector_type(8))) short short8;
typedef __attribute__((ext_vector_type(4))) float f32x4;

__device__ __forceinline__ unsigned short f2b(float f) {
  unsigned int u = __builtin_bit_cast(unsigned int, f);
  u += 0x7FFFu + ((u >> 16) & 1u);
  return (unsigned short)(u >> 16);
}
__device__ __forceinline__ float b2f(unsigned short s) {
  unsigned int u = ((unsigned int)s) << 16;
  return __builtin_bit_cast(float, u);
}
__device__ __forceinline__ f32x4 mfma16(short8 a, short8 b, f32x4 c) {
  return __builtin_amdgcn_mfma_f32_16x16x32_bf16(a, b, c, 0, 0, 0);
}
// fragment-ordered h layout: element offset of h[b][j] in hs
// frag (mt=b>>4, kk=j>>5) block of 64 lanes x 8 elems; lane = ((j>>3)&3)*16 + (b&15)
__device__ __forceinline__ int hsoff(int b, int j) {
  return (((b >> 4) * 16 + (j >> 5)) * 64 + (((j >> 3) & 3) * 16 + (b & 15))) * 8 + (j & 7);
}

/* ---------------- setup kernels ---------------- */

__global__ void k_cvt(const float* __restrict__ src, unsigned short* __restrict__ dst, int n4) {
  int i = blockIdx.x * blockDim.x + threadIdx.x;
  int stride = gridDim.x * blockDim.x;
  const float4* s4 = (const float4*)src;
  ushort4* d4 = (ushort4*)dst;
  for (; i < n4; i += stride) {
    float4 v = s4[i];
    ushort4 o;
    o.x = f2b(v.x); o.y = f2b(v.y); o.z = f2b(v.z); o.w = f2b(v.w);
    d4[i] = o;
  }
}

// src f32 (R,C) -> dst bf16 (C,R); R,C multiples of 64; grid (C/64, R/64), 256 thr
__global__ void k_transcvt(const float* __restrict__ src, unsigned short* __restrict__ dst, int R, int C) {
  __shared__ float tile[64][65];
  int cb = blockIdx.x * 64, rb = blockIdx.y * 64;
  int tx = threadIdx.x & 63, ty = threadIdx.x >> 6;
#pragma unroll
  for (int i = 0; i < 16; ++i) {
    int r = ty * 16 + i;
    tile[r][tx] = src[(size_t)(rb + r) * C + cb + tx];
  }
  __syncthreads();
#pragma unroll
  for (int i = 0; i < 16; ++i) {
    int c = ty * 16 + i;
    dst[(size_t)(cb + c) * R + rb + tx] = f2b(tile[tx][c]);
  }
}

// src f32 (R,C) -> dst f32 (C,R); grid (C/64, R/64)
__global__ void k_trans32(const float* __restrict__ src, float* __restrict__ dst, int R, int C) {
  __shared__ float tile[64][65];
  int cb = blockIdx.x * 64, rb = blockIdx.y * 64;
  int tx = threadIdx.x & 63, ty = threadIdx.x >> 6;
#pragma unroll
  for (int i = 0; i < 16; ++i) {
    int r = ty * 16 + i;
    tile[r][tx] = src[(size_t)(rb + r) * C + cb + tx];
  }
  __syncthreads();
#pragma unroll
  for (int i = 0; i < 16; ++i) {
    int c = ty * 16 + i;
    dst[(size_t)(cb + c) * R + rb + tx] = tile[tx][c];
  }
}

// dih (B,H) f32 -> hs fragment layout ; grid 64
__global__ void k_hs0(const float* __restrict__ src, unsigned short* __restrict__ hs) {
  int b = blockIdx.x;
  for (int j = threadIdx.x; j < H_; j += 256)
    hs[hsoff(b, j)] = f2b(src[(size_t)b * H_ + j]);
}

// epb[(b,l)][a] = sum_f encb[(b,l)][f] * WaTb[a][f] ; grid 200 blocks (64 rows each)
__global__ __launch_bounds__(256, 2) void k_encproj2(const unsigned short* __restrict__ encb,
                                                     const unsigned short* __restrict__ WaTb,
                                                     unsigned short* __restrict__ epb) {
  __shared__ unsigned short al[32768];  // 64 rows x 1024B, XOR-swizzled
  int tid = threadIdx.x;
  size_t rowbase = (size_t)blockIdx.x * 64;
  for (int idx = tid; idx < 4096; idx += 256) {
    int row = idx >> 6, seg = idx & 63;
    unsigned char* dp = (unsigned char*)al + row * 1024 + ((seg * 16) ^ ((row & 7) << 4));
    *(short8*)dp = *(const short8*)(encb + (rowbase + row) * F_ + seg * 8);
  }
  __syncthreads();
  int w = tid >> 6, lane = tid & 63, ln15 = lane & 15, g = lane >> 4;
  int sw = (ln15 & 7) << 4;
  const unsigned char* alb = (const unsigned char*)al;
  int mrow = w * 16 + ln15;
  for (int nt = 0; nt < 32; ++nt) {
    f32x4 acc = {0.f, 0.f, 0.f, 0.f};
    const unsigned short* brow = WaTb + (size_t)(nt * 16 + ln15) * F_ + 8 * g;
#pragma unroll 4
    for (int kk = 0; kk < 16; ++kk) {
      short8 bf = *(const short8*)(brow + kk * 32);
      short8 af = *(const short8*)(alb + mrow * 1024 + ((kk * 64 + 16 * g) ^ sw));
      acc = mfma16(af, bf, acc);
    }
#pragma unroll
    for (int r = 0; r < 4; ++r) {
      size_t m = rowbase + w * 16 + 4 * g + r;
      epb[m * A_ + nt * 16 + ln15] = f2b(acc[r]);
    }
  }
}

// out[:,0,:] = 0 ; grid (50, 64), 256 thr
__global__ void k_zero0(float* __restrict__ out) {
  int b = blockIdx.y;
  float* o = out + (size_t)b * T_ * V_;
  int v0 = blockIdx.x * 1024 + threadIdx.x;
#pragma unroll
  for (int i = 0; i < 4; ++i) { int v = v0 + i * 256; if (v < V_) o[v] = 0.f; }
}

/* ---------------- shared device code ---------------- */

struct CoopParams {
  const float* mask; const float* et;
  const unsigned short* encb; const unsigned short* epb;
  const unsigned short* WahT; const float* vatt;
  const unsigned short* Wihb; const unsigned short* Whhb;
  const float* bih; const float* bhh;
  const unsigned short* Wb; const float* bout;
  const int* ref;
  unsigned short* hs0; unsigned short* hs1;
  float* hT0; float* hT1;
  unsigned short* xbf;
  float* pm; float* ps; float* lse;
  float* out;
};

union CoopLds {
  struct {
    float hrow[H_];
    float hw[A_];
    float sc[256];
    float ctxp[4][F_];
  } att;
  struct { float lm[256]; float ls2[256]; } red;
};

// per-batch attention for step ts: emb + hW matvec + score + softmax + ctx -> xbf row
__device__ void attention_block(int b, int ts, const CoopParams& P,
                                const unsigned short* __restrict__ hs, CoopLds& S) {
  int tid = threadIdx.x;
  int word = P.ref[b * T_ + ts];
  const float* er = P.et + (size_t)word * E_;
  unsigned short* xrow = P.xbf + (size_t)b * D_;
  for (int k = tid; k < E_; k += 256) xrow[k] = f2b(er[k]);
  for (int k = tid; k < H_; k += 256) S.att.hrow[k] = b2f(hs[hsoff(b, k)]);
  __syncthreads();
  // hW[a] = sum_k h[b][k] * WahT[a][k]
  for (int a = tid; a < A_; a += 256) {
    const unsigned short* wr = P.WahT + (size_t)a * H_;
    float acc = 0.f;
    for (int k = 0; k < H_; k += 8) {
      short8 wv = *(const short8*)(wr + k);
#pragma unroll
      for (int j = 0; j < 8; ++j) acc += b2f((unsigned short)wv[j]) * S.att.hrow[k + j];
    }
    S.att.hw[a] = acc;
  }
  __syncthreads();
  int w = tid >> 6, lane = tid & 63;
  float hwv[8], vv[8];
#pragma unroll
  for (int j = 0; j < 8; ++j) { hwv[j] = S.att.hw[lane * 8 + j]; vv[j] = P.vatt[lane * 8 + j]; }
  for (int l = w; l < L_; l += 4) {
    short8 ev = *(const short8*)(P.epb + ((size_t)b * L_ + l) * A_ + lane * 8);
    float p = 0.f;
#pragma unroll
    for (int j = 0; j < 8; ++j) {
      float x = b2f((unsigned short)ev[j]) + hwv[j];
      float e2 = __expf(x + x);
      float th = 1.f - 2.f / (e2 + 1.f);
      p += th * vv[j];
    }
    for (int o = 1; o < 64; o <<= 1) p += __shfl_xor(p, o);
    if (lane == 0) {
      float mk = P.mask[b * L_ + l];
      S.att.sc[l] = (mk > 0.f) ? p : -1e9f;
    }
  }
  __syncthreads();
  if (tid < 64) {
    float m = -1e30f;
    for (int l = tid; l < L_; l += 64) m = fmaxf(m, S.att.sc[l]);
    for (int o = 1; o < 64; o <<= 1) m = fmaxf(m, __shfl_xor(m, o));
    float s = 0.f;
    for (int l = tid; l < L_; l += 64) s += __expf(S.att.sc[l] - m);
    for (int o = 1; o < 64; o <<= 1) s += __shfl_xor(s, o);
    float inv = 1.f / s;
    for (int l = tid; l < L_; l += 64) S.att.sc[l] = __expf(S.att.sc[l] - m) * inv;
  }
  __syncthreads();
  float cacc[8] = {0.f, 0.f, 0.f, 0.f, 0.f, 0.f, 0.f, 0.f};
  for (int l = w; l < L_; l += 4) {
    float aw = S.att.sc[l];
    short8 evv = *(const short8*)(P.encb + ((size_t)b * L_ + l) * F_ + lane * 8);
#pragma unroll
    for (int j = 0; j < 8; ++j) cacc[j] += aw * b2f((unsigned short)evv[j]);
  }
#pragma unroll
  for (int j = 0; j < 8; ++j) S.att.ctxp[w][lane * 8 + j] = cacc[j];
  __syncthreads();
  for (int f = tid; f < F_; f += 256) {
    float c = S.att.ctxp[0][f] + S.att.ctxp[1][f] + S.att.ctxp[2][f] + S.att.ctxp[3][f];
    xrow[E_ + f] = f2b(c);
  }
}

// GRU cell for 16 j-cols (bid<32)
__device__ void gru_block(int bid, const CoopParams& P,
                          const unsigned short* __restrict__ hsold, const float* __restrict__ hTold,
                          unsigned short* __restrict__ hsnew, float* __restrict__ hTnew) {
  int jb = bid * 16;
  int w = threadIdx.x >> 6, lane = threadIdx.x & 63;
  int ln15 = lane & 15, g = lane >> 4;
  f32x4 z4 = {0.f, 0.f, 0.f, 0.f};
  f32x4 aIr = z4, aIz = z4, aIn = z4, aHr = z4, aHz = z4, aHn = z4;
  {
    const unsigned short* xr = P.xbf + (size_t)(w * 16 + ln15) * D_ + 8 * g;
    const unsigned short* wir = P.Wihb + (size_t)(jb + ln15) * D_ + 8 * g;
    const unsigned short* wiz = P.Wihb + (size_t)(512 + jb + ln15) * D_ + 8 * g;
    const unsigned short* win = P.Wihb + (size_t)(1024 + jb + ln15) * D_ + 8 * g;
#pragma unroll 2
    for (int kk = 0; kk < 32; ++kk) {
      short8 xf = *(const short8*)(xr + kk * 32);
      aIr = mfma16(*(const short8*)(wir + kk * 32), xf, aIr);
      aIz = mfma16(*(const short8*)(wiz + kk * 32), xf, aIz);
      aIn = mfma16(*(const short8*)(win + kk * 32), xf, aIn);
    }
  }
  {
    const unsigned short* whr = P.Whhb + (size_t)(jb + ln15) * H_ + 8 * g;
    const unsigned short* whz = P.Whhb + (size_t)(512 + jb + ln15) * H_ + 8 * g;
    const unsigned short* whn = P.Whhb + (size_t)(1024 + jb + ln15) * H_ + 8 * g;
#pragma unroll 2
    for (int kk = 0; kk < 16; ++kk) {
      // B-fragment of h: rows w*16+ln15 (batch), cols kk*32+8g — fragment-ordered in hs
      short8 hf = *(const short8*)(hsold + ((w * 16 + kk) * 64 + lane) * 8);
      aHr = mfma16(*(const short8*)(whr + kk * 32), hf, aHr);
      aHz = mfma16(*(const short8*)(whz + kk * 32), hf, aHz);
      aHn = mfma16(*(const short8*)(whn + kk * 32), hf, aHn);
    }
  }
#pragma unroll
  for (int r = 0; r < 4; ++r) {
    int j = jb + 4 * g + r;
    int b = w * 16 + ln15;
    float ir = aIr[r] + P.bih[j];
    float iz = aIz[r] + P.bih[512 + j];
    float in_ = aIn[r] + P.bih[1024 + j];
    float hrv = aHr[r] + P.bhh[j];
    float hzv = aHz[r] + P.bhh[512 + j];
    float hnv = aHn[r] + P.bhh[1024 + j];
    float rg = 1.f / (1.f + __expf(-(ir + hrv)));
    float zg = 1.f / (1.f + __expf(-(iz + hzv)));
    float e2 = __expf(2.f * (in_ + rg * hnv));
    float ng = 1.f - 2.f / (e2 + 1.f);
    float ho = hTold[(size_t)j * B_ + b];
    float hv = (1.f - zg) * ng + zg * ho;
    hTnew[(size_t)j * B_ + b] = hv;
    hsnew[hsoff(b, j)] = f2b(hv);
  }
}

__device__ void lse_block(int b, const CoopParams& P, CoopLds& S) {
  int tid = threadIdx.x;
  float m = -1e38f, s = 0.f;
  for (int p = tid; p < NPART; p += 256) {
    float pmv = P.pm[b * NPART + p], psv = P.ps[b * NPART + p];
    float nm = fmaxf(m, pmv);
    s = s * __expf(m - nm) + psv * __expf(pmv - nm);
    m = nm;
  }
  S.red.lm[tid] = m; S.red.ls2[tid] = s;
  __syncthreads();
  for (int o = 128; o > 0; o >>= 1) {
    if (tid < o) {
      float m2 = S.red.lm[tid + o], s2 = S.red.ls2[tid + o];
      float nm = fmaxf(S.red.lm[tid], m2);
      S.red.ls2[tid] = S.red.ls2[tid] * __expf(S.red.lm[tid] - nm) + s2 * __expf(m2 - nm);
      S.red.lm[tid] = nm;
    }
    __syncthreads();
  }
  if (tid == 0) P.lse[b] = S.red.lm[0] + logf(S.red.ls2[0]);
}

// one 64-vocab-col tile of logits; A-fragments straight from fragment-ordered hs (global)
__device__ void gemm_tile(const CoopParams& P, const unsigned short* __restrict__ hs,
                          int tl, int plane, int tid) {
  int w = tid >> 6, lane = tid & 63;
  int ln15 = lane & 15, g = lane >> 4;
  int vcol = tl * 64 + w * 16 + ln15;
  bool vok = vcol < V_;
  int vr = vok ? vcol : (V_ - 1);
  f32x4 z4 = {0.f, 0.f, 0.f, 0.f};
  f32x4 acc[4] = {z4, z4, z4, z4};
  const unsigned short* brow = P.Wb + (size_t)vr * H_ + 8 * g;
#pragma unroll 4
  for (int kk = 0; kk < 16; ++kk) {
    short8 bf = *(const short8*)(brow + kk * 32);
#pragma unroll
    for (int mt = 0; mt < 4; ++mt) {
      short8 af = *(const short8*)(hs + ((mt * 16 + kk) * 64 + lane) * 8);
      acc[mt] = mfma16(af, bf, acc[mt]);
    }
  }
  float bo = P.bout[vr];
  int pbase = tl * 4 + w;
#pragma unroll
  for (int mt = 0; mt < 4; ++mt) {
#pragma unroll
    for (int r = 0; r < 4; ++r) {
      float val = acc[mt][r] + bo;
      int bi = mt * 16 + 4 * g + r;
      if (vok) P.out[((size_t)bi * T_ + plane) * V_ + vcol] = val;
      float pv = vok ? val : -1e30f;
      float mx = pv;
      for (int o = 1; o < 16; o <<= 1) mx = fmaxf(mx, __shfl_xor(mx, o));
      float e = __expf(pv - mx);
      for (int o = 1; o < 16; o <<= 1) e += __shfl_xor(e, o);
      if (ln15 == 0) {
        P.pm[bi * NPART + pbase] = mx;
        P.ps[bi * NPART + pbase] = e;
      }
    }
  }
}

__device__ void fin_tile(const CoopParams& P, int tl, int plane, int tid) {
  int b = tid >> 2;
  int c0 = tl * 64 + (tid & 3) * 16;
  float Lv = P.lse[b];
  float* o = P.out + ((size_t)b * T_ + plane) * V_;
#pragma unroll
  for (int i = 0; i < 16; ++i) {
    int c = c0 + i;
    if (c < V_) o[c] -= Lv;
  }
}

/* ---------------- cooperative kernel ---------------- */

__global__ __launch_bounds__(256, 2) void k_coop(CoopParams P) {
  __shared__ CoopLds S;
  cg::grid_group grid = cg::this_grid();
  int bid = blockIdx.x;
  int tid = threadIdx.x;
  const int NB = NB_COOP, NG = NG_COOP;
  unsigned short* hsbuf[2] = {P.hs0, P.hs1};
  float* hTbuf[2] = {P.hT0, P.hT1};

  if (bid >= NG) attention_block(bid - NG, 0, P, hsbuf[0], S);
  grid.sync();

  for (int t = 0; t < T_ - 1; ++t) {
    int cur = t & 1, nxt = cur ^ 1;
    // Phase1: GRU(t) || lse(plane t)
    if (bid < 32) gru_block(bid, P, hsbuf[cur], hTbuf[cur], hsbuf[nxt], hTbuf[nxt]);
    else if (bid >= 32 && bid < 96 && t >= 1) lse_block(bid - 32, P, S);
    grid.sync();
    // Phase2: logits(plane t+1) + fin(plane t) || attention(t+1)
    if (bid < NG) {
      for (int tl = bid; tl < NBLK_LOG; tl += NG) gemm_tile(P, hsbuf[nxt], tl, t + 1, tid);
      if (t >= 1) {
        for (int tl = bid; tl < NBLK_LOG; tl += NG) fin_tile(P, tl, t, tid);
      }
    } else if (t <= T_ - 3) {
      attention_block(bid - NG, t + 1, P, hsbuf[nxt], S);
    }
    grid.sync();
  }
  if (bid >= 32 && bid < 96) lse_block(bid - 32, P, S);
  grid.sync();
  for (int tl = bid; tl < NBLK_LOG; tl += NB) fin_tile(P, tl, T_ - 1, tid);
}

/* ---------------- fallback (normal-launch) kernels ---------------- */

__global__ __launch_bounds__(256) void k_att_s(CoopParams P, const unsigned short* hs, int ts) {
  __shared__ CoopLds S;
  attention_block(blockIdx.x, ts, P, hs, S);
}
__global__ __launch_bounds__(256) void k_gru_s(CoopParams P, const unsigned short* hsold,
                                               const float* hTold, unsigned short* hsnew,
                                               float* hTnew) {
  gru_block(blockIdx.x, P, hsold, hTold, hsnew, hTnew);
}
__global__ __launch_bounds__(256) void k_gemm_s(CoopParams P, const unsigned short* hs,
                                                int plane, int dofin) {
  gemm_tile(P, hs, blockIdx.x, plane, threadIdx.x);
  if (dofin) fin_tile(P, blockIdx.x, plane - 1, threadIdx.x);
}
__global__ __launch_bounds__(256) void k_lse_s(CoopParams P) {
  __shared__ CoopLds S;
  lse_block(blockIdx.x, P, S);
}
__global__ __launch_bounds__(256) void k_fin_s(CoopParams P, int plane) {
  fin_tile(P, blockIdx.x, plane, threadIdx.x);
}

/* ---------------- host ---------------- */

extern "C" void kernel_launch(void* const* d_in, const int* in_sizes, int n_in,
                              void* d_out, int out_size, void* d_ws, size_t ws_size,
                              hipStream_t stream) {
  const float* enc   = (const float*)d_in[0];
  const float* dih   = (const float*)d_in[1];
  const float* mask  = (const float*)d_in[2];
  const float* et    = (const float*)d_in[4];
  const float* Wih   = (const float*)d_in[5];
  const float* Whh   = (const float*)d_in[6];
  const float* bih   = (const float*)d_in[7];
  const float* bhh   = (const float*)d_in[8];
  const float* Waenc = (const float*)d_in[9];
  const float* Wah   = (const float*)d_in[10];
  const float* vatt  = (const float*)d_in[11];
  const float* Wout  = (const float*)d_in[12];
  const float* bout  = (const float*)d_in[13];
  const int*   ref   = (const int*)d_in[14];
  float* out = (float*)d_out;

  char* w = (char*)d_ws;
  size_t o = 0;
  unsigned short* Wb    = (unsigned short*)(w + o); o += (size_t)V_ * H_ * 2;
  unsigned short* Wihb  = (unsigned short*)(w + o); o += (size_t)1536 * 1024 * 2;
  unsigned short* Whhb  = (unsigned short*)(w + o); o += (size_t)1536 * 512 * 2;
  unsigned short* WaTb  = (unsigned short*)(w + o); o += (size_t)512 * 512 * 2;
  unsigned short* WahTb = (unsigned short*)(w + o); o += (size_t)512 * 512 * 2;
  unsigned short* encb  = (unsigned short*)(w + o); o += (size_t)B_ * L_ * F_ * 2;
  unsigned short* epb   = (unsigned short*)(w + o); o += (size_t)B_ * L_ * A_ * 2;
  float* hT0 = (float*)(w + o); o += (size_t)H_ * B_ * 4;
  float* hT1 = (float*)(w + o); o += (size_t)H_ * B_ * 4;
  unsigned short* hs0 = (unsigned short*)(w + o); o += (size_t)B_ * H_ * 2;
  unsigned short* hs1 = (unsigned short*)(w + o); o += (size_t)B_ * H_ * 2;
  unsigned short* xbf = (unsigned short*)(w + o); o += (size_t)B_ * D_ * 2;
  float* pm  = (float*)(w + o); o += (size_t)B_ * NPART * 4;
  float* ps  = (float*)(w + o); o += (size_t)B_ * NPART * 4;
  float* lse = (float*)(w + o); o += 256;

  k_cvt<<<4096, 256, 0, stream>>>(Wout, Wb, V_ * H_ / 4);
  k_cvt<<<1024, 256, 0, stream>>>(Wih, Wihb, 1536 * 1024 / 4);
  k_cvt<<<512, 256, 0, stream>>>(Whh, Whhb, 1536 * 512 / 4);
  k_cvt<<<2048, 256, 0, stream>>>(enc, encb, B_ * L_ * F_ / 4);
  k_transcvt<<<dim3(8, 8), 256, 0, stream>>>(Waenc, WaTb, 512, 512);
  k_transcvt<<<dim3(8, 8), 256, 0, stream>>>(Wah, WahTb, 512, 512);
  k_trans32<<<dim3(8, 1), 256, 0, stream>>>(dih, hT0, 64, 512);
  k_hs0<<<64, 256, 0, stream>>>(dih, hs0);
  k_encproj2<<<200, 256, 0, stream>>>(encb, WaTb, epb);
  k_zero0<<<dim3(50, 64), 256, 0, stream>>>(out);

  CoopParams cp;
  cp.mask = mask; cp.et = et;
  cp.encb = encb; cp.epb = epb;
  cp.WahT = WahTb; cp.vatt = vatt;
  cp.Wihb = Wihb; cp.Whhb = Whhb;
  cp.bih = bih; cp.bhh = bhh;
  cp.Wb = Wb; cp.bout = bout;
  cp.ref = ref;
  cp.hs0 = hs0; cp.hs1 = hs1;
  cp.hT0 = hT0; cp.hT1 = hT1;
  cp.xbf = xbf;
  cp.pm = pm; cp.ps = ps; cp.lse = lse;
  cp.out = out;

  void* args[] = {&cp};
  hipError_t err = hipLaunchCooperativeKernel((const void*)k_coop, dim3(NB_COOP), dim3(256),
                                              args, 0, stream);
  if (err != hipSuccess) {
    // fallback: same device code as normal launches
    unsigned short* hsb[2] = {hs0, hs1};
    float* hTb[2] = {hT0, hT1};
    for (int t = 0; t < T_ - 1; ++t) {
      int cur = t & 1, nxt = cur ^ 1;
      k_att_s<<<64, 256, 0, stream>>>(cp, hsb[cur], t);
      k_gru_s<<<32, 256, 0, stream>>>(cp, hsb[cur], hTb[cur], hsb[nxt], hTb[nxt]);
      k_gemm_s<<<NBLK_LOG, 256, 0, stream>>>(cp, hsb[nxt], t + 1, t >= 1 ? 1 : 0);
      k_lse_s<<<64, 256, 0, stream>>>(cp);
    }
    k_fin_s<<<NBLK_LOG, 256, 0, stream>>>(cp, T_ - 1);
  }
}

// Round 4
// 2611.370 us; speedup vs baseline: 2.0006x; 2.0006x over previous
//
#include <hip/hip_runtime.h>
#include <stdint.h>
#include <stddef.h>

#define B_ 64
#define L_ 200
#define F_ 512
#define H_ 512
#define A_ 512
#define E_ 512
#define V_ 50257
#define T_ 21
#define D_ 1024
#define NBLK_LOG 786   /* ceil(V/64) */
#define BH (B_ * H_)

typedef __attribute__((ext_vector_type(8))) short short8;
typedef __attribute__((ext_vector_type(4))) float f32x4;

__device__ __forceinline__ unsigned short f2b(float f) {
  unsigned int u = __builtin_bit_cast(unsigned int, f);
  u += 0x7FFFu + ((u >> 16) & 1u);
  return (unsigned short)(u >> 16);
}
__device__ __forceinline__ float b2f(unsigned short s) {
  unsigned int u = ((unsigned int)s) << 16;
  return __builtin_bit_cast(float, u);
}
__device__ __forceinline__ f32x4 mfma16(short8 a, short8 b, f32x4 c) {
  return __builtin_amdgcn_mfma_f32_16x16x32_bf16(a, b, c, 0, 0, 0);
}
// fragment-ordered h layout: element offset of h[b][j] within a plane
__device__ __forceinline__ int hsoff(int b, int j) {
  return (((b >> 4) * 16 + (j >> 5)) * 64 + (((j >> 3) & 3) * 16 + (b & 15))) * 8 + (j & 7);
}

/* ---------------- setup kernels ---------------- */

__global__ void k_cvt(const float* __restrict__ src, unsigned short* __restrict__ dst, int n4) {
  int i = blockIdx.x * blockDim.x + threadIdx.x;
  int stride = gridDim.x * blockDim.x;
  const float4* s4 = (const float4*)src;
  ushort4* d4 = (ushort4*)dst;
  for (; i < n4; i += stride) {
    float4 v = s4[i];
    ushort4 o;
    o.x = f2b(v.x); o.y = f2b(v.y); o.z = f2b(v.z); o.w = f2b(v.w);
    d4[i] = o;
  }
}

// src f32 (R,C) -> dst bf16 (C,R); R,C multiples of 64; grid (C/64, R/64), 256 thr
__global__ void k_transcvt(const float* __restrict__ src, unsigned short* __restrict__ dst, int R, int C) {
  __shared__ float tile[64][65];
  int cb = blockIdx.x * 64, rb = blockIdx.y * 64;
  int tx = threadIdx.x & 63, ty = threadIdx.x >> 6;
#pragma unroll
  for (int i = 0; i < 16; ++i) {
    int r = ty * 16 + i;
    tile[r][tx] = src[(size_t)(rb + r) * C + cb + tx];
  }
  __syncthreads();
#pragma unroll
  for (int i = 0; i < 16; ++i) {
    int c = ty * 16 + i;
    dst[(size_t)(cb + c) * R + rb + tx] = f2b(tile[tx][c]);
  }
}

// src f32 (R,C) -> dst f32 (C,R); grid (C/64, R/64)
__global__ void k_trans32(const float* __restrict__ src, float* __restrict__ dst, int R, int C) {
  __shared__ float tile[64][65];
  int cb = blockIdx.x * 64, rb = blockIdx.y * 64;
  int tx = threadIdx.x & 63, ty = threadIdx.x >> 6;
#pragma unroll
  for (int i = 0; i < 16; ++i) {
    int r = ty * 16 + i;
    tile[r][tx] = src[(size_t)(rb + r) * C + cb + tx];
  }
  __syncthreads();
#pragma unroll
  for (int i = 0; i < 16; ++i) {
    int c = ty * 16 + i;
    dst[(size_t)(cb + c) * R + rb + tx] = tile[tx][c];
  }
}

// dih (B,H) f32 -> hs fragment layout (plane 0) ; grid 64
__global__ void k_hs0(const float* __restrict__ src, unsigned short* __restrict__ hs) {
  int b = blockIdx.x;
  for (int j = threadIdx.x; j < H_; j += 256)
    hs[hsoff(b, j)] = f2b(src[(size_t)b * H_ + j]);
}

// epb[(b,l)][a] = sum_f encb[(b,l)][f] * WaTb[a][f] ; grid 200 blocks (64 rows each)
__global__ __launch_bounds__(256, 2) void k_encproj2(const unsigned short* __restrict__ encb,
                                                     const unsigned short* __restrict__ WaTb,
                                                     unsigned short* __restrict__ epb) {
  __shared__ unsigned short al[32768];  // 64 rows x 1024B, XOR-swizzled
  int tid = threadIdx.x;
  size_t rowbase = (size_t)blockIdx.x * 64;
  for (int idx = tid; idx < 4096; idx += 256) {
    int row = idx >> 6, seg = idx & 63;
    unsigned char* dp = (unsigned char*)al + row * 1024 + ((seg * 16) ^ ((row & 7) << 4));
    *(short8*)dp = *(const short8*)(encb + (rowbase + row) * F_ + seg * 8);
  }
  __syncthreads();
  int w = tid >> 6, lane = tid & 63, ln15 = lane & 15, g = lane >> 4;
  int sw = (ln15 & 7) << 4;
  const unsigned char* alb = (const unsigned char*)al;
  int mrow = w * 16 + ln15;
  for (int nt = 0; nt < 32; ++nt) {
    f32x4 acc = {0.f, 0.f, 0.f, 0.f};
    const unsigned short* brow = WaTb + (size_t)(nt * 16 + ln15) * F_ + 8 * g;
#pragma unroll 4
    for (int kk = 0; kk < 16; ++kk) {
      short8 bf = *(const short8*)(brow + kk * 32);
      short8 af = *(const short8*)(alb + mrow * 1024 + ((kk * 64 + 16 * g) ^ sw));
      acc = mfma16(af, bf, acc);
    }
#pragma unroll
    for (int r = 0; r < 4; ++r) {
      size_t m = rowbase + w * 16 + 4 * g + r;
      epb[m * A_ + nt * 16 + ln15] = f2b(acc[r]);
    }
  }
}

// out[:,0,:] = 0 ; grid (50, 64), 256 thr
__global__ void k_zero0(float* __restrict__ out) {
  int b = blockIdx.y;
  float* o = out + (size_t)b * T_ * V_;
  int v0 = blockIdx.x * 1024 + threadIdx.x;
#pragma unroll
  for (int i = 0; i < 4; ++i) { int v = v0 + i * 256; if (v < V_) o[v] = 0.f; }
}

/* ---------------- recurrence params ---------------- */

struct RecParams {
  const float* mask; const float* et;
  const unsigned short* encb; const unsigned short* epb;
  const unsigned short* WahT; const float* vatt;
  const unsigned short* Wihb; const unsigned short* Whhb;
  const float* bih; const float* bhh;
  const unsigned short* Wb; const float* bout;
  const int* ref;
  unsigned short* xbf;
  float* out;
};

/* ---------------- per-step kernels (normal launches) ---------------- */

// per-batch attention for step ts: emb + hW matvec + score + softmax + ctx -> xbf row
__global__ __launch_bounds__(256) void k_att(RecParams P, const unsigned short* __restrict__ hs,
                                             int ts) {
  __shared__ struct {
    float hrow[H_];
    float hw[A_];
    float sc[256];
    float ctxp[4][F_];
  } S;
  int b = blockIdx.x;
  int tid = threadIdx.x;
  int word = P.ref[b * T_ + ts];
  const float* er = P.et + (size_t)word * E_;
  unsigned short* xrow = P.xbf + (size_t)b * D_;
  for (int k = tid; k < E_; k += 256) xrow[k] = f2b(er[k]);
  for (int k = tid; k < H_; k += 256) S.hrow[k] = b2f(hs[hsoff(b, k)]);
  __syncthreads();
  // hW[a] = sum_k h[b][k] * WahT[a][k]
  for (int a = tid; a < A_; a += 256) {
    const unsigned short* wr = P.WahT + (size_t)a * H_;
    float acc = 0.f;
    for (int k = 0; k < H_; k += 8) {
      short8 wv = *(const short8*)(wr + k);
#pragma unroll
      for (int j = 0; j < 8; ++j) acc += b2f((unsigned short)wv[j]) * S.hrow[k + j];
    }
    S.hw[a] = acc;
  }
  __syncthreads();
  int w = tid >> 6, lane = tid & 63;
  float hwv[8], vv[8];
#pragma unroll
  for (int j = 0; j < 8; ++j) { hwv[j] = S.hw[lane * 8 + j]; vv[j] = P.vatt[lane * 8 + j]; }
  for (int l = w; l < L_; l += 4) {
    short8 ev = *(const short8*)(P.epb + ((size_t)b * L_ + l) * A_ + lane * 8);
    float p = 0.f;
#pragma unroll
    for (int j = 0; j < 8; ++j) {
      float x = b2f((unsigned short)ev[j]) + hwv[j];
      float e2 = __expf(x + x);
      float th = 1.f - 2.f / (e2 + 1.f);
      p += th * vv[j];
    }
    for (int o = 1; o < 64; o <<= 1) p += __shfl_xor(p, o);
    if (lane == 0) {
      float mk = P.mask[b * L_ + l];
      S.sc[l] = (mk > 0.f) ? p : -1e9f;
    }
  }
  __syncthreads();
  if (tid < 64) {
    float m = -1e30f;
    for (int l = tid; l < L_; l += 64) m = fmaxf(m, S.sc[l]);
    for (int o = 1; o < 64; o <<= 1) m = fmaxf(m, __shfl_xor(m, o));
    float s = 0.f;
    for (int l = tid; l < L_; l += 64) s += __expf(S.sc[l] - m);
    for (int o = 1; o < 64; o <<= 1) s += __shfl_xor(s, o);
    float inv = 1.f / s;
    for (int l = tid; l < L_; l += 64) S.sc[l] = __expf(S.sc[l] - m) * inv;
  }
  __syncthreads();
  float cacc[8] = {0.f, 0.f, 0.f, 0.f, 0.f, 0.f, 0.f, 0.f};
  for (int l = w; l < L_; l += 4) {
    float aw = S.sc[l];
    short8 evv = *(const short8*)(P.encb + ((size_t)b * L_ + l) * F_ + lane * 8);
#pragma unroll
    for (int j = 0; j < 8; ++j) cacc[j] += aw * b2f((unsigned short)evv[j]);
  }
#pragma unroll
  for (int j = 0; j < 8; ++j) S.ctxp[w][lane * 8 + j] = cacc[j];
  __syncthreads();
  for (int f = tid; f < F_; f += 256) {
    float c = S.ctxp[0][f] + S.ctxp[1][f] + S.ctxp[2][f] + S.ctxp[3][f];
    xrow[E_ + f] = f2b(c);
  }
}

// GRU cell for 16 j-cols per block ; grid 32
__global__ __launch_bounds__(256) void k_gru(RecParams P,
                                             const unsigned short* __restrict__ hsold,
                                             const float* __restrict__ hTold,
                                             unsigned short* __restrict__ hsnew,
                                             float* __restrict__ hTnew) {
  int jb = blockIdx.x * 16;
  int w = threadIdx.x >> 6, lane = threadIdx.x & 63;
  int ln15 = lane & 15, g = lane >> 4;
  f32x4 z4 = {0.f, 0.f, 0.f, 0.f};
  f32x4 aIr = z4, aIz = z4, aIn = z4, aHr = z4, aHz = z4, aHn = z4;
  {
    const unsigned short* xr = P.xbf + (size_t)(w * 16 + ln15) * D_ + 8 * g;
    const unsigned short* wir = P.Wihb + (size_t)(jb + ln15) * D_ + 8 * g;
    const unsigned short* wiz = P.Wihb + (size_t)(512 + jb + ln15) * D_ + 8 * g;
    const unsigned short* win = P.Wihb + (size_t)(1024 + jb + ln15) * D_ + 8 * g;
#pragma unroll 2
    for (int kk = 0; kk < 32; ++kk) {
      short8 xf = *(const short8*)(xr + kk * 32);
      aIr = mfma16(*(const short8*)(wir + kk * 32), xf, aIr);
      aIz = mfma16(*(const short8*)(wiz + kk * 32), xf, aIz);
      aIn = mfma16(*(const short8*)(win + kk * 32), xf, aIn);
    }
  }
  {
    const unsigned short* whr = P.Whhb + (size_t)(jb + ln15) * H_ + 8 * g;
    const unsigned short* whz = P.Whhb + (size_t)(512 + jb + ln15) * H_ + 8 * g;
    const unsigned short* whn = P.Whhb + (size_t)(1024 + jb + ln15) * H_ + 8 * g;
#pragma unroll 2
    for (int kk = 0; kk < 16; ++kk) {
      short8 hf = *(const short8*)(hsold + ((w * 16 + kk) * 64 + lane) * 8);
      aHr = mfma16(*(const short8*)(whr + kk * 32), hf, aHr);
      aHz = mfma16(*(const short8*)(whz + kk * 32), hf, aHz);
      aHn = mfma16(*(const short8*)(whn + kk * 32), hf, aHn);
    }
  }
#pragma unroll
  for (int r = 0; r < 4; ++r) {
    int j = jb + 4 * g + r;
    int b = w * 16 + ln15;
    float ir = aIr[r] + P.bih[j];
    float iz = aIz[r] + P.bih[512 + j];
    float in_ = aIn[r] + P.bih[1024 + j];
    float hrv = aHr[r] + P.bhh[j];
    float hzv = aHz[r] + P.bhh[512 + j];
    float hnv = aHn[r] + P.bhh[1024 + j];
    float rg = 1.f / (1.f + __expf(-(ir + hrv)));
    float zg = 1.f / (1.f + __expf(-(iz + hzv)));
    float e2 = __expf(2.f * (in_ + rg * hnv));
    float ng = 1.f - 2.f / (e2 + 1.f);
    float ho = hTold[(size_t)j * B_ + b];
    float hv = (1.f - zg) * ng + zg * ho;
    hTnew[(size_t)j * B_ + b] = hv;
    hsnew[hsoff(b, j)] = f2b(hv);
  }
}

/* ---------------- deferred logits: one big GEMM over all 20 planes ---------------- */
// M=1280 (20 planes x 64 batch), K=512, N=50257. Wb tile held in registers.
__global__ __launch_bounds__(256) void k_biggemm(RecParams P,
                                                 const unsigned short* __restrict__ hsAll) {
  int tid = threadIdx.x;
  int w = tid >> 6, lane = tid & 63;
  int ln15 = lane & 15, g = lane >> 4;
  int vcol = blockIdx.x * 64 + w * 16 + ln15;
  bool vok = vcol < V_;
  int vr = vok ? vcol : (V_ - 1);
  const unsigned short* brow = P.Wb + (size_t)vr * H_ + 8 * g;
  short8 wb[16];
#pragma unroll
  for (int kk = 0; kk < 16; ++kk) wb[kk] = *(const short8*)(brow + kk * 32);
  float bo = P.bout[vr];
  for (int t = 0; t < T_ - 1; ++t) {
    const unsigned short* hp = hsAll + (size_t)(t + 1) * BH;
#pragma unroll
    for (int mp = 0; mp < 2; ++mp) {
      f32x4 z4 = {0.f, 0.f, 0.f, 0.f};
      f32x4 acc0 = z4, acc1 = z4;
#pragma unroll
      for (int kk = 0; kk < 16; ++kk) {
        short8 a0 = *(const short8*)(hp + (((mp * 2 + 0) * 16 + kk) * 64 + lane) * 8);
        short8 a1 = *(const short8*)(hp + (((mp * 2 + 1) * 16 + kk) * 64 + lane) * 8);
        acc0 = mfma16(a0, wb[kk], acc0);
        acc1 = mfma16(a1, wb[kk], acc1);
      }
      if (vok) {
#pragma unroll
        for (int r = 0; r < 4; ++r) {
          int b0 = (mp * 2 + 0) * 16 + 4 * g + r;
          int b1 = (mp * 2 + 1) * 16 + 4 * g + r;
          P.out[((size_t)b0 * T_ + (t + 1)) * V_ + vcol] = acc0[r] + bo;
          P.out[((size_t)b1 * T_ + (t + 1)) * V_ + vcol] = acc1[r] + bo;
        }
      }
    }
  }
}

// fused LSE + subtract per output row ; grid 1280 (20 planes x 64 batch)
__global__ __launch_bounds__(256) void k_lsefin(float* __restrict__ out) {
  int rho = blockIdx.x;
  int b = rho / (T_ - 1), t = 1 + rho % (T_ - 1);
  float* o = out + ((size_t)b * T_ + t) * V_;
  int tid = threadIdx.x;
  float m = -1e30f, s = 0.f;
  for (int v = tid; v < V_; v += 256) {
    float x = o[v];
    float nm = fmaxf(m, x);
    s = s * __expf(m - nm) + __expf(x - nm);
    m = nm;
  }
  __shared__ float lm[256], ls[256];
  lm[tid] = m; ls[tid] = s;
  __syncthreads();
  for (int o2 = 128; o2 > 0; o2 >>= 1) {
    if (tid < o2) {
      float m2 = lm[tid + o2], s2 = ls[tid + o2];
      float nm = fmaxf(lm[tid], m2);
      ls[tid] = ls[tid] * __expf(lm[tid] - nm) + s2 * __expf(m2 - nm);
      lm[tid] = nm;
    }
    __syncthreads();
  }
  float Lv = lm[0] + logf(ls[0]);
  for (int v = tid; v < V_; v += 256) o[v] -= Lv;
}

/* ---------------- host ---------------- */

extern "C" void kernel_launch(void* const* d_in, const int* in_sizes, int n_in,
                              void* d_out, int out_size, void* d_ws, size_t ws_size,
                              hipStream_t stream) {
  const float* enc   = (const float*)d_in[0];
  const float* dih   = (const float*)d_in[1];
  const float* mask  = (const float*)d_in[2];
  const float* et    = (const float*)d_in[4];
  const float* Wih   = (const float*)d_in[5];
  const float* Whh   = (const float*)d_in[6];
  const float* bih   = (const float*)d_in[7];
  const float* bhh   = (const float*)d_in[8];
  const float* Waenc = (const float*)d_in[9];
  const float* Wah   = (const float*)d_in[10];
  const float* vatt  = (const float*)d_in[11];
  const float* Wout  = (const float*)d_in[12];
  const float* bout  = (const float*)d_in[13];
  const int*   ref   = (const int*)d_in[14];
  float* out = (float*)d_out;

  char* w = (char*)d_ws;
  size_t o = 0;
  unsigned short* Wb    = (unsigned short*)(w + o); o += (size_t)V_ * H_ * 2;
  unsigned short* Wihb  = (unsigned short*)(w + o); o += (size_t)1536 * 1024 * 2;
  unsigned short* Whhb  = (unsigned short*)(w + o); o += (size_t)1536 * 512 * 2;
  unsigned short* WaTb  = (unsigned short*)(w + o); o += (size_t)512 * 512 * 2;
  unsigned short* WahTb = (unsigned short*)(w + o); o += (size_t)512 * 512 * 2;
  unsigned short* encb  = (unsigned short*)(w + o); o += (size_t)B_ * L_ * F_ * 2;
  unsigned short* epb   = (unsigned short*)(w + o); o += (size_t)B_ * L_ * A_ * 2;
  unsigned short* hsAll = (unsigned short*)(w + o); o += (size_t)T_ * BH * 2;
  float* hT0 = (float*)(w + o); o += (size_t)H_ * B_ * 4;
  float* hT1 = (float*)(w + o); o += (size_t)H_ * B_ * 4;
  unsigned short* xbf = (unsigned short*)(w + o); o += (size_t)B_ * D_ * 2;

  k_cvt<<<4096, 256, 0, stream>>>(Wout, Wb, V_ * H_ / 4);
  k_cvt<<<1024, 256, 0, stream>>>(Wih, Wihb, 1536 * 1024 / 4);
  k_cvt<<<512, 256, 0, stream>>>(Whh, Whhb, 1536 * 512 / 4);
  k_cvt<<<2048, 256, 0, stream>>>(enc, encb, B_ * L_ * F_ / 4);
  k_transcvt<<<dim3(8, 8), 256, 0, stream>>>(Waenc, WaTb, 512, 512);
  k_transcvt<<<dim3(8, 8), 256, 0, stream>>>(Wah, WahTb, 512, 512);
  k_trans32<<<dim3(8, 1), 256, 0, stream>>>(dih, hT0, 64, 512);
  k_hs0<<<64, 256, 0, stream>>>(dih, hsAll);
  k_encproj2<<<200, 256, 0, stream>>>(encb, WaTb, epb);
  k_zero0<<<dim3(50, 64), 256, 0, stream>>>(out);

  RecParams rp;
  rp.mask = mask; rp.et = et;
  rp.encb = encb; rp.epb = epb;
  rp.WahT = WahTb; rp.vatt = vatt;
  rp.Wihb = Wihb; rp.Whhb = Whhb;
  rp.bih = bih; rp.bhh = bhh;
  rp.Wb = Wb; rp.bout = bout;
  rp.ref = ref;
  rp.xbf = xbf;
  rp.out = out;

  float* hTb[2] = {hT0, hT1};
  for (int t = 0; t < T_ - 1; ++t) {
    int cur = t & 1, nxt = cur ^ 1;
    unsigned short* hsold = hsAll + (size_t)t * BH;
    unsigned short* hsnew = hsAll + (size_t)(t + 1) * BH;
    k_att<<<64, 256, 0, stream>>>(rp, hsold, t);
    k_gru<<<32, 256, 0, stream>>>(rp, hsold, hTb[cur], hsnew, hTb[nxt]);
  }
  k_biggemm<<<NBLK_LOG, 256, 0, stream>>>(rp, hsAll);
  k_lsefin<<<1280, 256, 0, stream>>>(out);
}